// Round 7
// baseline (30.394 us; speedup 1.0000x reference)
//
#include <hip/hip_runtime.h>
#include <math.h>

// RoI max pooling: feats (1,256,128,128) f32, rois (1,256,4) int32 {x,y,w,h},
// out (N=256, C=256, 7, 7) f32.  One wave per (n, channel-PAIR).
//
// Lane map (load phase): q = lane&7 (column quad), b = lane>>3 (row bin,
// b==7 inactive). Each lane loads ALL rows of its bin for its quad with
// dup-row clamp idx=min(dr, nr-1) (operand multiset == reference's masked
// dr in range(MAX_BIN=8)) -> rowmax completes in-register, no cross-lane
// ops. TWO channels per wave: planes share all geometry; interleaved load
// streams double in-flight VMEM (latency hiding) and amortize setup.
// Two quad slots cover cols [0,64): slot1 = 4q, slot2 = 32+4q; slot2
// skipped wave-uniformly when wa<=32. Masked lanes use dup addr 0 (same
// cache lines as q=0 -> no extra traffic). ds_write_b128 per slot/channel.
//
// Read phase: lane l=i*7+j IS the output offset; per channel reads
// lds[ch][i][pad+sxr..+7], masks t<wj (MAX_BIN clamp), 7 maxes, one
// contiguous 196B store. Same-wave DS in-order -> lgkmcnt(0), no barrier.

constexpr int kC = 256, kH = 128, kW = 128, kN = 256, kOut = 7;
constexpr int kStr = 68;  // dwords/bin-row: 16B-aligned, bank base 4*bin

__device__ __forceinline__ float4 fmax4(float4 a, const float4 b) {
  a.x = fmaxf(a.x, b.x); a.y = fmaxf(a.y, b.y);
  a.z = fmaxf(a.z, b.z); a.w = fmaxf(a.w, b.w);
  return a;
}

template <bool Q2>
__device__ __forceinline__ void load_phase2(
    const float* __restrict__ p0, const float* __restrict__ p1,
    const int nrb, const int nrm1, const int c1, const int c2,
    const bool a1, const bool a2, const int bin,
    float* __restrict__ w0, float* __restrict__ w1) {
  float4 m10 = *(const float4*)(p0 + c1);
  float4 m11 = *(const float4*)(p1 + c1);
  float4 m20, m21;
  if (Q2) { m20 = *(const float4*)(p0 + c2); m21 = *(const float4*)(p1 + c2); }
#pragma unroll
  for (int dr = 1; dr < 8; ++dr) {
    if (dr < nrb) {                                      // uniform row skip
      const int rofs = ((dr <= nrm1) ? dr : nrm1) << 7;  // dup-row clamp
      m10 = fmax4(m10, *(const float4*)(p0 + rofs + c1));
      m11 = fmax4(m11, *(const float4*)(p1 + rofs + c1));
      if (Q2) {
        m20 = fmax4(m20, *(const float4*)(p0 + rofs + c2));
        m21 = fmax4(m21, *(const float4*)(p1 + rofs + c2));
      }
    }
  }
  if (a1) {
    *(float4*)(w0 + bin * kStr + c1) = m10;
    *(float4*)(w1 + bin * kStr + c1) = m11;
  }
  if (Q2) {
    if (a2) {
      *(float4*)(w0 + bin * kStr + c2) = m20;
      *(float4*)(w1 + bin * kStr + c2) = m21;
    }
  }
}

__global__ __launch_bounds__(256) void roipool_kernel(
    const float* __restrict__ feats,
    const int* __restrict__ rois,
    float* __restrict__ out) {
  __shared__ float lds[4][2][7 * kStr];  // 15232 B

  const int lane = threadIdx.x & 63;
  const int wid  = __builtin_amdgcn_readfirstlane(threadIdx.x) >> 6;
  const int bid  = blockIdx.x;

  // XCD-affine mapping (perf heuristic): xcd = bid & 7, n-fastest per cgrp
  const int xcd  = bid & 7;
  const int idx  = bid >> 3;
  const int n    = idx & (kN - 1);
  const int cgrp = ((idx >> 8) << 3) | xcd;   // 0..31
  const int c0   = (cgrp << 3) | (wid << 1);  // 8 channels/block, 2/wave

  const int4 roi = ((const int4*)rois)[n];
  const int x = __builtin_amdgcn_readfirstlane(roi.x);
  const int y = __builtin_amdgcn_readfirstlane(roi.y);
  const int w = __builtin_amdgcn_readfirstlane(roi.z);
  const int h = __builtin_amdgcn_readfirstlane(roi.w);

  const int xa  = x & ~3;
  const int pad = x - xa;
  const int wa  = pad + w;          // <= 59

  const int q  = lane & 7;          // column-quad slot
  const int b  = lane >> 3;         // row-bin slot; b==7 inactive
  const int bc = (b < 7) ? b : 6;   // safe dup bin (writes masked)

  // per-lane bin row bounds
  const int bh   = bc * h;
  const int s_b  = bh / 7;
  int nr         = (bh + h + 6) / 7 - s_b;
  if (nr > 8) nr = 8;               // MAX_BIN clamp
  const int nrm1 = nr - 1;
  const int sy_b = y + s_b;

  int nrb = (h + 12) / 7;           // uniform: nrb >= every bin's nr
  if (nrb > 8) nrb = 8;

  const int c1r = 4 * q;
  const int c2r = 32 + 4 * q;
  const bool a1 = (b < 7) && (c1r < wa);
  const bool a2 = (b < 7) && (c2r < wa);
  const int c1 = a1 ? c1r : 0;      // safe dup address when masked
  const int c2 = a2 ? c2r : 0;

  const float* __restrict__ p0 =
      feats + (((unsigned)c0 << 14) + ((unsigned)sy_b << 7) + (unsigned)xa);
  const float* __restrict__ p1 = p0 + (1u << 14);

  float* __restrict__ w0 = lds[wid][0];
  float* __restrict__ w1 = lds[wid][1];
  if (wa > 32) load_phase2<true >(p0, p1, nrb, nrm1, c1, c2, a1, a2, bc, w0, w1);
  else         load_phase2<false>(p0, p1, nrb, nrm1, c1, c2, a1, a2, bc, w0, w1);

  // drain LDS writes before cross-lane reads (same-wave, no barrier)
  asm volatile("s_waitcnt lgkmcnt(0)" ::: "memory");

  // read phase: lane l = i*7 + j -> output offset directly (shared geometry)
  const int l49 = (lane < 49) ? lane : 48;
  const int i   = (l49 * 37) >> 8;                 // floor(l49/7)
  const int j   = l49 - i * 7;
  const int jw  = j * w;
  const int sxr = (jw * 9363) >> 16;               // floor(jw/7)
  const int exr = ((jw + w + 6) * 9363) >> 16;     // floor(((j+1)w+6)/7)
  int wj = exr - sxr;
  if (wj > 8) wj = 8;                              // MAX_BIN clamp
  const int robs = i * kStr + pad + sxr;

#pragma unroll
  for (int ch = 0; ch < 2; ++ch) {
    const float* __restrict__ rbase = lds[wid][ch] + robs;
    float acc = rbase[0];                          // t=0 always valid
#pragma unroll
    for (int t = 1; t < 8; ++t) {
      const float v = rbase[t];
      acc = fmaxf(acc, (t < wj) ? v : -INFINITY);  // cndmask discards junk
    }
    if (lane < 49)
      out[((size_t)n * kC + (c0 + ch)) * 49 + lane] = acc;
  }
}

extern "C" void kernel_launch(void* const* d_in, const int* in_sizes, int n_in,
                              void* d_out, int out_size, void* d_ws, size_t ws_size,
                              hipStream_t stream) {
  const float* feats = (const float*)d_in[0];
  const int*   rois  = (const int*)d_in[1];
  float*       out   = (float*)d_out;
  dim3 grid((kC / 8) * kN);   // 8192 blocks: 8 channels per block, 2 per wave
  dim3 block(256);
  roipool_kernel<<<grid, block, 0, stream>>>(feats, rois, out);
}